// Round 2
// baseline (74078.204 us; speedup 1.0000x reference)
//
#include <hip/hip_runtime.h>
#include <hip/hip_bf16.h>
#include <hip/hip_cooperative_groups.h>

#define HID   1024
#define BATCH 512
#define SEQ   256
#define OUTD  64
#define KCAT  2048
#define NGATE 4096

typedef __attribute__((ext_vector_type(8))) short bf16x8;
typedef __attribute__((ext_vector_type(4))) float f32x4;

__device__ __forceinline__ unsigned short f2bf(float v) {
  union { float f; unsigned u; } u; u.f = v;
  unsigned r = u.u + 0x7fffu + ((u.u >> 16) & 1u);
  return (unsigned short)(r >> 16);
}
__device__ __forceinline__ float bf2f(unsigned short b) {
  union { unsigned u; float f; } u; u.u = ((unsigned)b) << 16;
  return u.f;
}
__device__ __forceinline__ float sigf(float x) {
  return 1.0f / (1.0f + __expf(-x));
}
__device__ __forceinline__ float tanh_fast(float x) {
  float ax = fabsf(x);
  float e = __expf(-2.0f * ax);
  float r = (1.0f - e) / (1.0f + e);
  return copysignf(r, x);
}

// ---------------- prepass kernels ----------------

// Wcat0[n'][k] : k<1024 -> W_hh0[orig][k] ; k>=1024 -> Weff[orig][k-1024] = W_ih0 @ fc_out_w
// n' = 4*j + g interleave (orig = g*1024 + j) so each N-tile owns complete cells.
__global__ void k_build_wcat0(const float* __restrict__ Whh0, const float* __restrict__ Wih0,
                              const float* __restrict__ fcw, unsigned short* __restrict__ wcat0) {
  int np = blockIdx.x;
  int j = np >> 2, g = np & 3;
  int orig = g * 1024 + j;
  int tid = threadIdx.x;
  const float* src = Whh0 + (size_t)orig * 1024;
  unsigned short* dst = wcat0 + (size_t)np * KCAT;
  for (int k = tid; k < 1024; k += 256) dst[k] = f2bf(src[k]);
  __shared__ float wrow[64];
  if (tid < 64) wrow[tid] = Wih0[orig * 64 + tid];
  __syncthreads();
  for (int k = tid; k < 1024; k += 256) {
    float acc = 0.f;
#pragma unroll
    for (int o = 0; o < 64; ++o) acc += wrow[o] * fcw[o * 1024 + k];
    dst[1024 + k] = f2bf(acc);
  }
}

__global__ void k_build_wcat1(const float* __restrict__ Wih1, const float* __restrict__ Whh1,
                              unsigned short* __restrict__ wcat1) {
  int np = blockIdx.x;
  int j = np >> 2, g = np & 3;
  int orig = g * 1024 + j;
  int tid = threadIdx.x;
  unsigned short* dst = wcat1 + (size_t)np * KCAT;
  const float* s0 = Wih1 + (size_t)orig * 1024;
  const float* s1 = Whh1 + (size_t)orig * 1024;
  for (int k = tid; k < 1024; k += 256) {
    dst[k]        = f2bf(s0[k]);
    dst[1024 + k] = f2bf(s1[k]);
  }
}

__global__ void k_build_bias(const float* bih0, const float* bhh0,
                             const float* bih1, const float* bhh1,
                             const float* Wih0, const float* fcb,
                             float* bias0b, float* bias0x, float* bias1) {
  int np = blockIdx.x * 256 + threadIdx.x;
  if (np >= NGATE) return;
  int j = np >> 2, g = np & 3;
  int orig = g * 1024 + j;
  bias0b[np] = bih0[orig] + bhh0[orig];
  bias1[np]  = bih1[orig] + bhh1[orig];
  float acc = 0.f;
#pragma unroll
  for (int o = 0; o < 64; ++o) acc += Wih0[orig * 64 + o] * fcb[o];
  bias0x[np] = acc;   // fc_out bias routed through W_ih0 (valid only t>=1; x(0)=0)
}

__global__ void k_fcwt(const float* __restrict__ fcw, float* __restrict__ fcwT) {
  int idx = blockIdx.x * 256 + threadIdx.x;  // 65536
  int k = idx >> 6, o = idx & 63;
  fcwT[k * 64 + o] = fcw[o * 1024 + k];
}

// init_flat = [z_style|z_skill] @ fc_init_w^T + b ; torch-.view scatter:
// l=0 -> bufA cols [0,1024) (h0 prev); l=1 -> bufB cols [1024,2048) (h1 prev)
__global__ void k_init(const float* __restrict__ zs, const float* __restrict__ zk,
                       const float* __restrict__ fiw, const float* __restrict__ fib,
                       unsigned short* __restrict__ bufA, unsigned short* __restrict__ bufB,
                       float* __restrict__ c0, float* __restrict__ c1) {
  int r = blockIdx.x;   // 0..511 rows of init_flat
  int tid = threadIdx.x;
  __shared__ float z[256];
  if (tid < 128) z[tid] = zs[r * 128 + tid];
  else           z[tid] = zk[r * 128 + (tid - 128)];
  __syncthreads();
  for (int h = tid; h < 1024; h += 256) {
    c0[r * 1024 + h] = 0.f;
    c1[r * 1024 + h] = 0.f;
    bufA[r * KCAT + 1024 + h] = 0;   // h1x = 0 => x(0) = 0 (Weff * 0)
  }
  for (int c = tid; c < 2048; c += 256) {
    float acc = fib[c];
    const float* w = fiw + (size_t)c * 256;
#pragma unroll 8
    for (int k = 0; k < 256; ++k) acc += z[k] * w[k];
    int l = (r >= 256) ? 1 : 0;
    int b = 2 * (r - l * 256) + (c >> 10);
    int h = c & 1023;
    unsigned short v = f2bf(acc);
    if (l == 0) bufA[b * KCAT + h] = v;
    else        bufB[b * KCAT + 1024 + h] = v;
  }
}

// ---------------- main cooperative kernel ----------------

struct Params {
  const unsigned short* wcat0;
  const unsigned short* wcat1;
  const float* bias0b;
  const float* bias0x;
  const float* bias1;
  unsigned short* bufA;   // [512][2048] : [h0_prev | h1_prev(x-source)]
  unsigned short* bufB;   // [512][2048] : [h0_new  | h1_prev(recurrent)]
  float* c0;
  float* c1;
  const float* fcwT;      // [1024][64]
  const float* fcb;
  float* out;             // [512][256][64]
};

__shared__ float g_slab[4 * 32 * 68];   // 34816 B static LDS

// One 64x128 tile of gates = A[512,2048] @ W[4096,2048]^T, then fused LSTM cell.
__device__ __forceinline__ void gemm_cell(
    const unsigned short* __restrict__ A, const unsigned short* __restrict__ W,
    const float* __restrict__ bias, const float* __restrict__ bias2,
    float* __restrict__ cst, unsigned short* __restrict__ hdst, int hcol0,
    int blk, int tid)
{
  const int lane = tid & 63, wave = tid >> 6;
  const int m0 = (blk >> 5) * 64;
  const int n0 = (blk & 31) * 128;
  const int wm = (wave & 1) * 32;
  const int wn = (wave >> 1) * 64;
  const int lr = lane & 15;    // row within 16-frag
  const int lq = lane >> 4;    // quad
  const unsigned short* Ab = A + (size_t)(m0 + wm + lr) * KCAT + lq * 8;
  const unsigned short* Wb = W + (size_t)(n0 + wn + lr) * KCAT + lq * 8;

  f32x4 acc[2][4];
#pragma unroll
  for (int i = 0; i < 2; ++i)
#pragma unroll
    for (int j = 0; j < 4; ++j) acc[i][j] = (f32x4){0.f, 0.f, 0.f, 0.f};

#pragma unroll 2
  for (int kk = 0; kk < KCAT; kk += 32) {
    bf16x8 a0 = *(const bf16x8*)(Ab + kk);
    bf16x8 a1 = *(const bf16x8*)(Ab + 16 * KCAT + kk);
    bf16x8 b0 = *(const bf16x8*)(Wb + kk);
    bf16x8 b1 = *(const bf16x8*)(Wb + 16 * KCAT + kk);
    bf16x8 b2 = *(const bf16x8*)(Wb + 32 * KCAT + kk);
    bf16x8 b3 = *(const bf16x8*)(Wb + 48 * KCAT + kk);
    acc[0][0] = __builtin_amdgcn_mfma_f32_16x16x32_bf16(a0, b0, acc[0][0], 0, 0, 0);
    acc[0][1] = __builtin_amdgcn_mfma_f32_16x16x32_bf16(a0, b1, acc[0][1], 0, 0, 0);
    acc[0][2] = __builtin_amdgcn_mfma_f32_16x16x32_bf16(a0, b2, acc[0][2], 0, 0, 0);
    acc[0][3] = __builtin_amdgcn_mfma_f32_16x16x32_bf16(a0, b3, acc[0][3], 0, 0, 0);
    acc[1][0] = __builtin_amdgcn_mfma_f32_16x16x32_bf16(a1, b0, acc[1][0], 0, 0, 0);
    acc[1][1] = __builtin_amdgcn_mfma_f32_16x16x32_bf16(a1, b1, acc[1][1], 0, 0, 0);
    acc[1][2] = __builtin_amdgcn_mfma_f32_16x16x32_bf16(a1, b2, acc[1][2], 0, 0, 0);
    acc[1][3] = __builtin_amdgcn_mfma_f32_16x16x32_bf16(a1, b3, acc[1][3], 0, 0, 0);
  }

  // dump gates to per-wave LDS slab [32][68] (C layout: row=quad*4+reg, col=lane&15)
  float* slab = g_slab + wave * (32 * 68);
#pragma unroll
  for (int mi = 0; mi < 2; ++mi)
#pragma unroll
    for (int ni = 0; ni < 4; ++ni)
#pragma unroll
      for (int r2 = 0; r2 < 4; ++r2)
        slab[(16 * mi + lq * 4 + r2) * 68 + 16 * ni + lr] = acc[mi][ni][r2];
  __syncthreads();

  // fused cell: each lane handles 8 (m, j) cells of its wave's 16 hidden units
  const int jl = lane & 15;
  const int jg = (n0 + wn) / 4 + jl;   // global hidden index
  float bi = bias[4 * jg + 0], bf_ = bias[4 * jg + 1];
  float bg = bias[4 * jg + 2], bo = bias[4 * jg + 3];
  if (bias2) {
    bi += bias2[4 * jg + 0]; bf_ += bias2[4 * jg + 1];
    bg += bias2[4 * jg + 2]; bo += bias2[4 * jg + 3];
  }
#pragma unroll
  for (int r2 = 0; r2 < 8; ++r2) {
    int mrow = lq * 8 + r2;
    int m = m0 + wm + mrow;
    float gi = slab[mrow * 68 + 4 * jl + 0] + bi;
    float gf = slab[mrow * 68 + 4 * jl + 1] + bf_;
    float gg = slab[mrow * 68 + 4 * jl + 2] + bg;
    float go = slab[mrow * 68 + 4 * jl + 3] + bo;
    float iv = sigf(gi), fv = sigf(gf), gv = tanh_fast(gg), ov = sigf(go);
    float cold = cst[m * 1024 + jg];
    float cnew = fv * cold + iv * gv;
    float hnew = ov * tanh_fast(cnew);
    cst[m * 1024 + jg] = cnew;
    hdst[(size_t)m * KCAT + hcol0 + jg] = f2bf(hnew);
  }
  __syncthreads();
}

// out(tq) for this block's 2 batch rows: out = h1 @ fc_out_w^T + b, h1 from bufA.h1
// Uses no LDS; 128 threads (2 rows x 64 outs), runs during phase A (bufA read-only).
__device__ __forceinline__ void out_slice(const Params& p, int blk, int tid, int tq) {
  if (tid < 128) {
    int o = tid & 63, rb = tid >> 6;
    int b = 2 * blk + rb;
    const unsigned short* h = p.bufA + (size_t)b * KCAT + 1024;
    float acc = 0.f;
    for (int k = 0; k < 1024; k += 8) {
      bf16x8 hv = *(const bf16x8*)(h + k);
#pragma unroll
      for (int j = 0; j < 8; ++j)
        acc += bf2f(((unsigned short*)&hv)[j]) * p.fcwT[(k + j) * 64 + o];
    }
    p.out[((size_t)b * SEQ + tq) * OUTD + o] = acc + p.fcb[o];
  }
}

__global__ __launch_bounds__(256)
void k_lstm(Params p) {
  namespace cg = cooperative_groups;
  cg::grid_group grid = cg::this_grid();
  const int blk = blockIdx.x, tid = threadIdx.x;

  for (int t = 0; t < SEQ; ++t) {
    // ---- phase A: gates0 = [h0_prev|h1_prev] @ Wcat0^T ; cell0 -> h0_new into bufB ----
    if (t > 0) {
      // stage h1_prev for phase B recurrence (skip t=0: bufB.h1 holds init)
      int r = 2 * blk + (tid >> 7);
      int c = (tid & 127) * 8;
      *(bf16x8*)&p.bufB[r * KCAT + 1024 + c] = *(const bf16x8*)&p.bufA[r * KCAT + 1024 + c];
      out_slice(p, blk, tid, t - 1);   // out(t-1) from h1(t-1), off critical path work
    }
    gemm_cell(p.bufA, p.wcat0, p.bias0b, (t > 0) ? p.bias0x : nullptr,
              p.c0, p.bufB, 0, blk, tid);
    grid.sync();
    // ---- phase B: gates1 = [h0_new|h1_prev] @ Wcat1^T ; cell1 -> h1_new into bufA ----
    {
      int r = 2 * blk + (tid >> 7);
      int c = (tid & 127) * 8;
      *(bf16x8*)&p.bufA[r * KCAT + c] = *(const bf16x8*)&p.bufB[r * KCAT + c];  // h0 -> next step
    }
    gemm_cell(p.bufB, p.wcat1, p.bias1, nullptr,
              p.c1, p.bufA, 1024, blk, tid);
    grid.sync();
  }
  out_slice(p, blk, tid, SEQ - 1);
}

// ---------------- launch ----------------

extern "C" void kernel_launch(void* const* d_in, const int* in_sizes, int n_in,
                              void* d_out, int out_size, void* d_ws, size_t ws_size,
                              hipStream_t stream) {
  const float* zs   = (const float*)d_in[0];
  const float* zk   = (const float*)d_in[1];
  const float* fiw  = (const float*)d_in[2];
  const float* fib  = (const float*)d_in[3];
  const float* Wih0 = (const float*)d_in[4];
  const float* Whh0 = (const float*)d_in[5];
  const float* bih0 = (const float*)d_in[6];
  const float* bhh0 = (const float*)d_in[7];
  const float* Wih1 = (const float*)d_in[8];
  const float* Whh1 = (const float*)d_in[9];
  const float* bih1 = (const float*)d_in[10];
  const float* bhh1 = (const float*)d_in[11];
  const float* fcw  = (const float*)d_in[12];
  const float* fcb  = (const float*)d_in[13];
  float* out = (float*)d_out;

  char* ws = (char*)d_ws;
  size_t off = 0;
  auto alloc = [&](size_t bytes) -> char* {
    char* p = ws + off;
    off += (bytes + 255) & ~(size_t)255;
    return p;
  };
  unsigned short* wcat0 = (unsigned short*)alloc((size_t)NGATE * KCAT * 2);
  unsigned short* wcat1 = (unsigned short*)alloc((size_t)NGATE * KCAT * 2);
  unsigned short* bufA  = (unsigned short*)alloc((size_t)BATCH * KCAT * 2);
  unsigned short* bufB  = (unsigned short*)alloc((size_t)BATCH * KCAT * 2);
  float* c0     = (float*)alloc((size_t)BATCH * HID * 4);
  float* c1     = (float*)alloc((size_t)BATCH * HID * 4);
  float* bias0b = (float*)alloc(NGATE * 4);
  float* bias0x = (float*)alloc(NGATE * 4);
  float* bias1  = (float*)alloc(NGATE * 4);
  float* fcwT   = (float*)alloc((size_t)HID * OUTD * 4);

  hipLaunchKernelGGL(k_build_wcat0, dim3(NGATE), dim3(256), 0, stream, Whh0, Wih0, fcw, wcat0);
  hipLaunchKernelGGL(k_build_wcat1, dim3(NGATE), dim3(256), 0, stream, Wih1, Whh1, wcat1);
  hipLaunchKernelGGL(k_build_bias, dim3(16), dim3(256), 0, stream,
                     bih0, bhh0, bih1, bhh1, Wih0, fcb, bias0b, bias0x, bias1);
  hipLaunchKernelGGL(k_fcwt, dim3(256), dim3(256), 0, stream, fcw, fcwT);
  hipLaunchKernelGGL(k_init, dim3(BATCH), dim3(256), 0, stream, zs, zk, fiw, fib, bufA, bufB, c0, c1);

  Params prm;
  prm.wcat0 = wcat0; prm.wcat1 = wcat1;
  prm.bias0b = bias0b; prm.bias0x = bias0x; prm.bias1 = bias1;
  prm.bufA = bufA; prm.bufB = bufB;
  prm.c0 = c0; prm.c1 = c1;
  prm.fcwT = fcwT; prm.fcb = fcb; prm.out = out;
  void* args[] = { &prm };
  hipLaunchCooperativeKernel((void*)k_lstm, dim3(256), dim3(256), args, 0, stream);
}

// Round 3
// 55580.542 us; speedup vs baseline: 1.3328x; 1.3328x over previous
//
#include <hip/hip_runtime.h>
#include <hip/hip_bf16.h>
#include <hip/hip_cooperative_groups.h>

#define HID   1024
#define BATCH 512
#define SEQ   256
#define OUTD  64
#define KCAT  2048
#define NGATE 4096

typedef __attribute__((ext_vector_type(8))) short bf16x8;
typedef __attribute__((ext_vector_type(4))) float f32x4;
typedef unsigned short u16;

// dynamic LDS: [0,64K) W0 frags, [64K,128K) W1 frags, [128K,+10K) gate slabs
#define LDS_BYTES (131072 + 8 * 1280)

__device__ __forceinline__ u16 f2bf(float v) {
  union { float f; unsigned u; } u; u.f = v;
  unsigned r = u.u + 0x7fffu + ((u.u >> 16) & 1u);
  return (u16)(r >> 16);
}
__device__ __forceinline__ float bf2f(u16 b) {
  union { unsigned u; float f; } u; u.u = ((unsigned)b) << 16;
  return u.f;
}
__device__ __forceinline__ float sigf(float x) { return 1.0f / (1.0f + __expf(-x)); }
__device__ __forceinline__ float tanh_fast(float x) {
  float ax = fabsf(x);
  float e = __expf(-2.0f * ax);
  return copysignf((1.0f - e) / (1.0f + e), x);
}

// fragment-order index for W slabs: block b=np>>4 owns gate rows [16b,16b+16).
// frag f=k>>5 (512 elems, 1KB): elem[(q*16+nl)*8+e] = W[n'=16b+nl][k=f*32+q*8+e]
__device__ __forceinline__ size_t fragidx(int np, int k) {
  int b = np >> 4, nl = np & 15;
  int f = k >> 5, q = (k >> 3) & 3, e = k & 7;
  return ((size_t)b * 64 + f) * 512 + (q * 16 + nl) * 8 + e;
}

// ---------------- prepass kernels ----------------

// W0cat rows (gate-interleaved n'=4j+g): k<1024 -> W_hh0 ; k>=1024 -> Weff = W_ih0 @ fc_out_w
__global__ void k_build_w0f(const float* __restrict__ Whh0, const float* __restrict__ Wih0,
                            const float* __restrict__ fcw, u16* __restrict__ w0f) {
  int np = blockIdx.x;
  int j = np >> 2, g = np & 3;
  int orig = g * 1024 + j;
  int tid = threadIdx.x;
  __shared__ float wrow[64];
  if (tid < 64) wrow[tid] = Wih0[orig * 64 + tid];
  __syncthreads();
  for (int k = tid; k < 1024; k += 256) {
    w0f[fragidx(np, k)] = f2bf(Whh0[(size_t)orig * 1024 + k]);
    float acc = 0.f;
#pragma unroll
    for (int o = 0; o < 64; ++o) acc += wrow[o] * fcw[o * 1024 + k];
    w0f[fragidx(np, 1024 + k)] = f2bf(acc);
  }
}

// W1cat rows: k<1024 -> W_ih1 ; k>=1024 -> W_hh1
__global__ void k_build_w1f(const float* __restrict__ Wih1, const float* __restrict__ Whh1,
                            u16* __restrict__ w1f) {
  int np = blockIdx.x;
  int j = np >> 2, g = np & 3;
  int orig = g * 1024 + j;
  int tid = threadIdx.x;
  for (int k = tid; k < 1024; k += 256) {
    w1f[fragidx(np, k)]        = f2bf(Wih1[(size_t)orig * 1024 + k]);
    w1f[fragidx(np, 1024 + k)] = f2bf(Whh1[(size_t)orig * 1024 + k]);
  }
}

__global__ void k_build_bias(const float* bih0, const float* bhh0,
                             const float* bih1, const float* bhh1,
                             const float* Wih0, const float* fcb,
                             float* bias0b, float* bias0x, float* bias1) {
  int np = blockIdx.x * 256 + threadIdx.x;
  if (np >= NGATE) return;
  int j = np >> 2, g = np & 3;
  int orig = g * 1024 + j;
  bias0b[np] = bih0[orig] + bhh0[orig];
  bias1[np]  = bih1[orig] + bhh1[orig];
  float acc = 0.f;
#pragma unroll
  for (int o = 0; o < 64; ++o) acc += Wih0[orig * 64 + o] * fcb[o];
  bias0x[np] = acc;   // fc_out bias routed through W_ih0 (valid only t>=1; x(0)=0)
}

// init_flat = [z_style|z_skill] @ fc_init_w^T + b ; torch-.view scatter:
// l=0 -> bufA cols [0,1024) (h0 prev); l=1 -> bufB cols [1024,2048) (h1 prev)
__global__ void k_init(const float* __restrict__ zs, const float* __restrict__ zk,
                       const float* __restrict__ fiw, const float* __restrict__ fib,
                       u16* __restrict__ bufA, u16* __restrict__ bufB) {
  int r = blockIdx.x;
  int tid = threadIdx.x;
  __shared__ float z[256];
  if (tid < 128) z[tid] = zs[r * 128 + tid];
  else           z[tid] = zk[r * 128 + (tid - 128)];
  __syncthreads();
  for (int h = tid; h < 1024; h += 256)
    bufA[r * KCAT + 1024 + h] = 0;   // h1x = 0 => x(0) = 0
  for (int c = tid; c < 2048; c += 256) {
    float acc = fib[c];
    const float* w = fiw + (size_t)c * 256;
#pragma unroll 8
    for (int k = 0; k < 256; ++k) acc += z[k] * w[k];
    int l = (r >= 256) ? 1 : 0;
    int b = 2 * (r - l * 256) + (c >> 10);
    int h = c & 1023;
    u16 v = f2bf(acc);
    if (l == 0) bufA[b * KCAT + h] = v;
    else        bufB[b * KCAT + 1024 + h] = v;
  }
}

// ---------------- main cooperative kernel ----------------

struct Params {
  const u16* w0f;        // frag-ordered, 16MB
  const u16* w1f;
  const float* bias0b;
  const float* bias0x;
  const float* bias1;
  u16* bufA;             // [512][2048] : [h0_prev | h1_prev(x-source)]
  u16* bufB;             // [512][2048] : [h0_new  | h1_prev(recurrent)]
  float* c0s;            // [256 blk][8 wave][4 mf][64 lane] block-private cell state
  float* c1s;
  const float* fcw;      // [64][1024] original layout
  const float* fcb;
  float* out;            // [512][256][64]
};

// gates tile [512 m x 16 n] = A[512,2048] @ Wslice^T with LDS-persistent W frags,
// then fused LSTM cell. Wave w owns m rows [64w, 64w+64).
__device__ __forceinline__ void gemm_cell_p(
    const u16* __restrict__ A, const u16* __restrict__ lw,
    float* __restrict__ cblk, u16* __restrict__ hdst, int hcol0,
    const float* b_g, const float* bx_g, bool use_bx,
    int blk, int lane, int wave, float* slab)
{
  const int lr = lane & 15, lq = lane >> 4;
  const u16* Ab = A + (size_t)(wave * 64 + lr) * KCAT + lq * 8;
  const u16* Wb = lw + lane * 8;

  f32x4 acc0 = {0,0,0,0}, acc1 = {0,0,0,0}, acc2 = {0,0,0,0}, acc3 = {0,0,0,0};
#pragma unroll 4
  for (int f = 0; f < 64; ++f) {
    bf16x8 wf = *(const bf16x8*)(Wb + f * 512);
    bf16x8 a0 = *(const bf16x8*)(Ab + f * 32);
    bf16x8 a1 = *(const bf16x8*)(Ab + 16 * KCAT + f * 32);
    bf16x8 a2 = *(const bf16x8*)(Ab + 32 * KCAT + f * 32);
    bf16x8 a3 = *(const bf16x8*)(Ab + 48 * KCAT + f * 32);
    acc0 = __builtin_amdgcn_mfma_f32_16x16x32_bf16(a0, wf, acc0, 0, 0, 0);
    acc1 = __builtin_amdgcn_mfma_f32_16x16x32_bf16(a1, wf, acc1, 0, 0, 0);
    acc2 = __builtin_amdgcn_mfma_f32_16x16x32_bf16(a2, wf, acc2, 0, 0, 0);
    acc3 = __builtin_amdgcn_mfma_f32_16x16x32_bf16(a3, wf, acc3, 0, 0, 0);
  }

  // per-wave slab round-trip (no barrier: wave-synchronous DS ops):
  // write C layout (row=q*4+reg, col=lane&15), read 4 gates of one cell as b128
  const int rr = lane & 3, jl = (lane >> 2) & 3;
  f32x4 accs[4] = {acc0, acc1, acc2, acc3};
#pragma unroll
  for (int mf = 0; mf < 4; ++mf) {
#pragma unroll
    for (int r2 = 0; r2 < 4; ++r2)
      slab[(lq * 4 + r2) * 20 + lr] = accs[mf][r2];
    f32x4 g4 = *(f32x4*)&slab[(lq * 4 + rr) * 20 + 4 * jl];
    float gi = g4[0] + b_g[0] + (use_bx ? bx_g[0] : 0.f);
    float gf = g4[1] + b_g[1] + (use_bx ? bx_g[1] : 0.f);
    float gg = g4[2] + b_g[2] + (use_bx ? bx_g[2] : 0.f);
    float go = g4[3] + b_g[3] + (use_bx ? bx_g[3] : 0.f);
    float iv = sigf(gi), fv = sigf(gf), gv = tanh_fast(gg), ov = sigf(go);
    int cidx = (wave * 4 + mf) * 64 + lane;
    float cold = cblk[cidx];
    float cnew = fv * cold + iv * gv;
    float hnew = ov * tanh_fast(cnew);
    cblk[cidx] = cnew;
    int m = wave * 64 + mf * 16 + lq * 4 + rr;
    hdst[(size_t)m * KCAT + hcol0 + blk * 4 + jl] = f2bf(hnew);
  }
}

// out(tq) for this block's 2 batch rows, spread over all 8 waves:
// wave covers 16 dots; 4 lanes k-split each dot, shuffle-reduced.
__device__ __forceinline__ void out_proj(const Params& p, int blk, int lane, int wave, int tq) {
  int dl = lane >> 2, ks = lane & 3;
  int dg = wave * 16 + dl;            // 0..127
  int row = dg >> 6, o = dg & 63;
  int b = 2 * blk + row;
  const u16* h = p.bufA + (size_t)b * KCAT + 1024 + ks * 256;
  const float* w = p.fcw + (size_t)o * 1024 + ks * 256;
  float acc = 0.f;
#pragma unroll 4
  for (int kk = 0; kk < 256; kk += 8) {
    bf16x8 hv = *(const bf16x8*)(h + kk);
    float4 w0 = *(const float4*)(w + kk);
    float4 w1 = *(const float4*)(w + kk + 4);
    acc += bf2f(((u16*)&hv)[0]) * w0.x + bf2f(((u16*)&hv)[1]) * w0.y
         + bf2f(((u16*)&hv)[2]) * w0.z + bf2f(((u16*)&hv)[3]) * w0.w
         + bf2f(((u16*)&hv)[4]) * w1.x + bf2f(((u16*)&hv)[5]) * w1.y
         + bf2f(((u16*)&hv)[6]) * w1.z + bf2f(((u16*)&hv)[7]) * w1.w;
  }
  acc += __shfl_xor(acc, 1);
  acc += __shfl_xor(acc, 2);
  if (ks == 0) p.out[((size_t)b * SEQ + tq) * OUTD + o] = acc + p.fcb[o];
}

__global__ __launch_bounds__(512)
void k_lstm(Params p) {
  namespace cg = cooperative_groups;
  cg::grid_group grid = cg::this_grid();
  extern __shared__ char smem[];
  const int blk = blockIdx.x, tid = threadIdx.x;
  const int lane = tid & 63, wave = tid >> 6;

  u16* lw0 = (u16*)smem;
  u16* lw1 = (u16*)(smem + 65536);
  float* slab = (float*)(smem + 131072) + wave * 320;   // 16 rows x 20 floats per wave

  // one-time: block's W slices -> LDS (linear, frag-ordered)
  {
    const u16* g0 = p.w0f + (size_t)blk * 32768;
    const u16* g1 = p.w1f + (size_t)blk * 32768;
    for (int i = tid * 8; i < 32768; i += 512 * 8) {
      *(bf16x8*)(lw0 + i) = *(const bf16x8*)(g0 + i);
      *(bf16x8*)(lw1 + i) = *(const bf16x8*)(g1 + i);
    }
  }
  // per-lane bias preload (lane's unit jg is fixed for the whole sequence)
  const int jg = blk * 4 + ((lane >> 2) & 3);
  float b0r[4], bxr[4], b1r[4];
#pragma unroll
  for (int g = 0; g < 4; ++g) {
    b0r[g] = p.bias0b[4 * jg + g];
    bxr[g] = p.bias0x[4 * jg + g];
    b1r[g] = p.bias1[4 * jg + g];
  }
  float* c0blk = p.c0s + (size_t)blk * 2048;
  float* c1blk = p.c1s + (size_t)blk * 2048;
  __syncthreads();

  for (int t = 0; t < SEQ; ++t) {
    // ---- phase A: gates0 = [h0_prev|h1_prev] @ W0^T ; cell0 -> h0_new into bufB ----
    if (t > 0) {
      if (tid < 256) {   // stage h1_prev for phase B recurrence
        int r = 2 * blk + (tid >> 7);
        int c = (tid & 127) * 8;
        *(bf16x8*)&p.bufB[r * KCAT + 1024 + c] = *(const bf16x8*)&p.bufA[r * KCAT + 1024 + c];
      }
      out_proj(p, blk, lane, wave, t - 1);   // out(t-1) from bufA.h1 (read-only now)
    }
    gemm_cell_p(p.bufA, lw0, c0blk, p.bufB, 0, b0r, bxr, t > 0, blk, lane, wave, slab);
    grid.sync();
    // ---- phase B: gates1 = [h0_new|h1_prev] @ W1^T ; cell1 -> h1_new into bufA ----
    if (tid < 256) {     // h0_new -> bufA for next step's phase A
      int r = 2 * blk + (tid >> 7);
      int c = (tid & 127) * 8;
      *(bf16x8*)&p.bufA[r * KCAT + c] = *(const bf16x8*)&p.bufB[r * KCAT + c];
    }
    gemm_cell_p(p.bufB, lw1, c1blk, p.bufA, 1024, b1r, nullptr, false, blk, lane, wave, slab);
    grid.sync();
  }
  out_proj(p, blk, lane, wave, SEQ - 1);
}

// ---------------- launch ----------------

extern "C" void kernel_launch(void* const* d_in, const int* in_sizes, int n_in,
                              void* d_out, int out_size, void* d_ws, size_t ws_size,
                              hipStream_t stream) {
  const float* zs   = (const float*)d_in[0];
  const float* zk   = (const float*)d_in[1];
  const float* fiw  = (const float*)d_in[2];
  const float* fib  = (const float*)d_in[3];
  const float* Wih0 = (const float*)d_in[4];
  const float* Whh0 = (const float*)d_in[5];
  const float* bih0 = (const float*)d_in[6];
  const float* bhh0 = (const float*)d_in[7];
  const float* Wih1 = (const float*)d_in[8];
  const float* Whh1 = (const float*)d_in[9];
  const float* bih1 = (const float*)d_in[10];
  const float* bhh1 = (const float*)d_in[11];
  const float* fcw  = (const float*)d_in[12];
  const float* fcb  = (const float*)d_in[13];
  float* out = (float*)d_out;

  char* ws = (char*)d_ws;
  size_t off = 0;
  auto alloc = [&](size_t bytes) -> char* {
    char* pp = ws + off;
    off += (bytes + 255) & ~(size_t)255;
    return pp;
  };
  u16* w0f  = (u16*)alloc((size_t)NGATE * KCAT * 2);
  u16* w1f  = (u16*)alloc((size_t)NGATE * KCAT * 2);
  u16* bufA = (u16*)alloc((size_t)BATCH * KCAT * 2);
  u16* bufB = (u16*)alloc((size_t)BATCH * KCAT * 2);
  float* c0s    = (float*)alloc((size_t)256 * 2048 * 4);
  float* c1s    = (float*)alloc((size_t)256 * 2048 * 4);
  float* bias0b = (float*)alloc(NGATE * 4);
  float* bias0x = (float*)alloc(NGATE * 4);
  float* bias1  = (float*)alloc(NGATE * 4);

  hipMemsetAsync(c0s, 0, (size_t)256 * 2048 * 4, stream);
  hipMemsetAsync(c1s, 0, (size_t)256 * 2048 * 4, stream);

  hipLaunchKernelGGL(k_build_w0f, dim3(NGATE), dim3(256), 0, stream, Whh0, Wih0, fcw, w0f);
  hipLaunchKernelGGL(k_build_w1f, dim3(NGATE), dim3(256), 0, stream, Wih1, Whh1, w1f);
  hipLaunchKernelGGL(k_build_bias, dim3(16), dim3(256), 0, stream,
                     bih0, bhh0, bih1, bhh1, Wih0, fcb, bias0b, bias0x, bias1);
  hipLaunchKernelGGL(k_init, dim3(BATCH), dim3(256), 0, stream, zs, zk, fiw, fib, bufA, bufB);

  Params prm;
  prm.w0f = w0f; prm.w1f = w1f;
  prm.bias0b = bias0b; prm.bias0x = bias0x; prm.bias1 = bias1;
  prm.bufA = bufA; prm.bufB = bufB;
  prm.c0s = c0s; prm.c1s = c1s;
  prm.fcw = fcw; prm.fcb = fcb; prm.out = out;

  hipFuncSetAttribute((const void*)k_lstm, hipFuncAttributeMaxDynamicSharedMemorySize, LDS_BYTES);
  void* args[] = { &prm };
  hipLaunchCooperativeKernel((void*)k_lstm, dim3(256), dim3(512), args, LDS_BYTES, stream);
}

// Round 4
// 38757.864 us; speedup vs baseline: 1.9113x; 1.4340x over previous
//
#include <hip/hip_runtime.h>
#include <hip/hip_bf16.h>
#include <hip/hip_cooperative_groups.h>

#define HID   1024
#define BATCH 512
#define SEQ   256
#define OUTD  64
#define NGATE 4096
#define NBLK  256
#define NTHR  512

typedef __attribute__((ext_vector_type(8))) short bf16x8;
typedef __attribute__((ext_vector_type(4))) float f32x4;
typedef unsigned short u16;

// dynamic LDS: [0,64K) W0 frags, [64K,128K) W1 frags, [128K,+10K) gate slabs
#define LDS_BYTES (131072 + 8 * 1280)

__device__ __forceinline__ u16 f2bf(float v) {
  union { float f; unsigned u; } u; u.f = v;
  unsigned r = u.u + 0x7fffu + ((u.u >> 16) & 1u);
  return (u16)(r >> 16);
}
__device__ __forceinline__ float bf2f(u16 b) {
  union { unsigned u; float f; } u; u.u = ((unsigned)b) << 16;
  return u.f;
}
__device__ __forceinline__ float sigf(float x) { return 1.0f / (1.0f + __expf(-x)); }
__device__ __forceinline__ float tanh_fast(float x) {
  float ax = fabsf(x);
  float e = __expf(-2.0f * ax);
  return copysignf((1.0f - e) / (1.0f + e), x);
}

// fragment-order index for W slabs: block b=np>>4 owns gate rows [16b,16b+16).
// frag f=k>>5 (512 elems, 1KB): elem[(q*16+nl)*8+e] = W[n'=16b+nl][k=f*32+q*8+e]
__device__ __forceinline__ size_t fragidx(int np, int k) {
  int b = np >> 4, nl = np & 15;
  int f = k >> 5, q = (k >> 3) & 3, e = k & 7;
  return ((size_t)b * 64 + f) * 512 + (q * 16 + nl) * 8 + e;
}

// ---------------- prepass kernels ----------------

// W0cat rows (gate-interleaved n'=4j+g): k<1024 -> W_hh0 ; k>=1024 -> Weff = W_ih0 @ fc_out_w
__global__ void k_build_w0f(const float* __restrict__ Whh0, const float* __restrict__ Wih0,
                            const float* __restrict__ fcw, u16* __restrict__ w0f) {
  int np = blockIdx.x;
  int j = np >> 2, g = np & 3;
  int orig = g * 1024 + j;
  int tid = threadIdx.x;
  __shared__ float wrow[64];
  if (tid < 64) wrow[tid] = Wih0[orig * 64 + tid];
  __syncthreads();
  for (int k = tid; k < 1024; k += 256) {
    w0f[fragidx(np, k)] = f2bf(Whh0[(size_t)orig * 1024 + k]);
    float acc = 0.f;
#pragma unroll
    for (int o = 0; o < 64; ++o) acc += wrow[o] * fcw[o * 1024 + k];
    w0f[fragidx(np, 1024 + k)] = f2bf(acc);
  }
}

// W1cat rows: k<1024 -> W_ih1 ; k>=1024 -> W_hh1
__global__ void k_build_w1f(const float* __restrict__ Wih1, const float* __restrict__ Whh1,
                            u16* __restrict__ w1f) {
  int np = blockIdx.x;
  int j = np >> 2, g = np & 3;
  int orig = g * 1024 + j;
  int tid = threadIdx.x;
  for (int k = tid; k < 1024; k += 256) {
    w1f[fragidx(np, k)]        = f2bf(Wih1[(size_t)orig * 1024 + k]);
    w1f[fragidx(np, 1024 + k)] = f2bf(Whh1[(size_t)orig * 1024 + k]);
  }
}

__global__ void k_build_bias(const float* bih0, const float* bhh0,
                             const float* bih1, const float* bhh1,
                             const float* Wih0, const float* fcb,
                             float* bias0b, float* bias0x, float* bias1) {
  int np = blockIdx.x * 256 + threadIdx.x;
  if (np >= NGATE) return;
  int j = np >> 2, g = np & 3;
  int orig = g * 1024 + j;
  bias0b[np] = bih0[orig] + bhh0[orig];
  bias1[np]  = bih1[orig] + bhh1[orig];
  float acc = 0.f;
#pragma unroll
  for (int o = 0; o < 64; ++o) acc += Wih0[orig * 64 + o] * fcb[o];
  bias0x[np] = acc;   // fc_out bias routed through W_ih0 (valid only t>=1; x(0)=0)
}

__global__ void k_fcwb(const float* __restrict__ fcw, u16* __restrict__ fcwb) {
  int idx = blockIdx.x * 256 + threadIdx.x;  // 65536
  fcwb[idx] = f2bf(fcw[idx]);
}

// init_flat = [z_style|z_skill] @ fc_init_w^T + b ; torch-.view scatter:
// l=0 -> h0init[b][h] ; l=1 -> h1init[b][h]. Also zero h1z (x(0)=0 source).
__global__ void k_init(const float* __restrict__ zs, const float* __restrict__ zk,
                       const float* __restrict__ fiw, const float* __restrict__ fib,
                       u16* __restrict__ h0i, u16* __restrict__ h1z, u16* __restrict__ h1i) {
  int r = blockIdx.x;   // 0..511
  int tid = threadIdx.x;
  __shared__ float z[256];
  if (tid < 128) z[tid] = zs[r * 128 + tid];
  else           z[tid] = zk[r * 128 + (tid - 128)];
  __syncthreads();
  for (int h = tid; h < 1024; h += 256) h1z[(size_t)r * 1024 + h] = 0;
  for (int c = tid; c < 2048; c += 256) {
    float acc = fib[c];
    const float* w = fiw + (size_t)c * 256;
#pragma unroll 8
    for (int k = 0; k < 256; ++k) acc += z[k] * w[k];
    int l = (r >= 256) ? 1 : 0;
    int b = 2 * (r - l * 256) + (c >> 10);
    int h = c & 1023;
    u16 v = f2bf(acc);
    if (l == 0) h0i[(size_t)b * 1024 + h] = v;
    else        h1i[(size_t)b * 1024 + h] = v;
  }
}

// ---------------- main cooperative kernel ----------------

struct Params {
  const u16* w0f;
  const u16* w1f;
  const float* bias0b;
  const float* bias0x;
  const float* bias1;
  u16* h0a; u16* h0b;    // h0 double buffer [512][1024]
  u16* h1a; u16* h1b;    // h1 double buffer
  u16* h1i;              // h1 init (recurrent operand at t=0 only)
  const u16* fcwb;       // [64][1024] bf16
  const float* fcb;
  float* out;            // [512][256][64]
  unsigned* flags;       // [512 intervals][256 blocks]
};

// lightweight grid barrier: per-interval flag array, wave-0 polls with agent loads
__device__ __forceinline__ void gbar(unsigned* flags, int i, int blk, int tid) {
  __syncthreads();
  if (tid < 64) {
    unsigned* f = flags + i * NBLK;
    if (tid == 0) {
      __builtin_amdgcn_fence(__ATOMIC_RELEASE, "agent");
      __hip_atomic_store(&f[blk], 1u, __ATOMIC_RELAXED, __HIP_MEMORY_SCOPE_AGENT);
    }
    while (true) {
      unsigned a = __hip_atomic_load(&f[tid],       __ATOMIC_RELAXED, __HIP_MEMORY_SCOPE_AGENT);
      unsigned b = __hip_atomic_load(&f[tid + 64],  __ATOMIC_RELAXED, __HIP_MEMORY_SCOPE_AGENT);
      unsigned c = __hip_atomic_load(&f[tid + 128], __ATOMIC_RELAXED, __HIP_MEMORY_SCOPE_AGENT);
      unsigned d = __hip_atomic_load(&f[tid + 192], __ATOMIC_RELAXED, __HIP_MEMORY_SCOPE_AGENT);
      if (__ballot((a & b & c & d) == 1u) == ~0ull) break;
      __builtin_amdgcn_s_sleep(2);
    }
    if (tid == 0) __builtin_amdgcn_fence(__ATOMIC_ACQUIRE, "agent");
  }
  __syncthreads();
}

// gates tile [512 m x 16 n] = [Ah0|Ah1] @ Wslice^T, LDS-persistent W, prefetch depth 2,
// then fused LSTM cell with register-resident cell state.
__device__ __forceinline__ void gemm_cell(
    const u16* __restrict__ Ah0, const u16* __restrict__ Ah1,
    const u16* __restrict__ lw, float* cr,
    u16* __restrict__ hdst, const float* bg, const float* bx, bool ubx,
    int blk, int lane, int wave, float* slab)
{
  const int lr = lane & 15, lq = lane >> 4;
  const u16* p0 = Ah0 + (size_t)(wave * 64 + lr) * 1024 + lq * 8;
  const u16* p1 = Ah1 + (size_t)(wave * 64 + lr) * 1024 + lq * 8;
  const u16* Wb = lw + lane * 8;
  const int q0 = blk & 15;   // chunk rotation spreads L2 fills across blocks

  f32x4 a0 = {0,0,0,0}, a1 = {0,0,0,0}, a2 = {0,0,0,0}, a3 = {0,0,0,0};
  bf16x8 buf[2][4][4];   // [slot][j][row]: 2 chunks in flight (128 VGPR)

  auto LD = [&](int slot, int q) {
    const u16* bp = (q < 8) ? (p0 + q * 128) : (p1 + (q - 8) * 128);
#pragma unroll
    for (int j = 0; j < 4; ++j)
#pragma unroll
      for (int r = 0; r < 4; ++r)
        buf[slot][j][r] = *(const bf16x8*)(bp + j * 32 + r * 16 * 1024);
  };

  LD(0, q0);
  LD(1, (q0 + 1) & 15);
#pragma unroll
  for (int c = 0; c < 16; ++c) {
    const int q = (q0 + c) & 15;
    const int slot = c & 1;
#pragma unroll
    for (int j = 0; j < 4; ++j) {
      bf16x8 wf = *(const bf16x8*)(Wb + (4 * q + j) * 512);
      a0 = __builtin_amdgcn_mfma_f32_16x16x32_bf16(buf[slot][j][0], wf, a0, 0, 0, 0);
      a1 = __builtin_amdgcn_mfma_f32_16x16x32_bf16(buf[slot][j][1], wf, a1, 0, 0, 0);
      a2 = __builtin_amdgcn_mfma_f32_16x16x32_bf16(buf[slot][j][2], wf, a2, 0, 0, 0);
      a3 = __builtin_amdgcn_mfma_f32_16x16x32_bf16(buf[slot][j][3], wf, a3, 0, 0, 0);
    }
    if (c < 14) LD(slot, (q0 + c + 2) & 15);
  }

  // per-wave slab round-trip (wave-synchronous, no barrier):
  // write C layout (row=quad*4+reg, col=lane&15), read 4 gates of one cell as b128
  const int rr = lane & 3, jl = (lane >> 2) & 3;
  f32x4 accs[4] = {a0, a1, a2, a3};
#pragma unroll
  for (int mf = 0; mf < 4; ++mf) {
#pragma unroll
    for (int r2 = 0; r2 < 4; ++r2)
      slab[(lq * 4 + r2) * 20 + lr] = accs[mf][r2];
    f32x4 g4 = *(f32x4*)&slab[(lq * 4 + rr) * 20 + 4 * jl];
    float gi = g4[0] + bg[0] + (ubx ? bx[0] : 0.f);
    float gf = g4[1] + bg[1] + (ubx ? bx[1] : 0.f);
    float gg = g4[2] + bg[2] + (ubx ? bx[2] : 0.f);
    float go = g4[3] + bg[3] + (ubx ? bx[3] : 0.f);
    float iv = sigf(gi), fv = sigf(gf), gv = tanh_fast(gg), ov = sigf(go);
    float cnew = fv * cr[mf] + iv * gv;
    float hnew = ov * tanh_fast(cnew);
    cr[mf] = cnew;
    int m = wave * 64 + mf * 16 + lq * 4 + rr;
    hdst[(size_t)m * 1024 + blk * 4 + jl] = f2bf(hnew);
  }
}

// out(tq) for this block's 2 batch rows over all 8 waves; 4-lane k-split + shuffle.
__device__ __forceinline__ void out_proj(const u16* __restrict__ h1s, const Params& p,
                                         int blk, int lane, int wave, int tq) {
  int dl = lane >> 2, ks = lane & 3;
  int dg = wave * 16 + dl;            // 0..127
  int row = dg >> 6, o = dg & 63;
  int b = 2 * blk + row;
  const u16* h = h1s + (size_t)b * 1024 + ks * 256;
  const u16* w = p.fcwb + (size_t)o * 1024 + ks * 256;
  float acc = 0.f;
#pragma unroll 4
  for (int kk = 0; kk < 256; kk += 8) {
    bf16x8 hv = *(const bf16x8*)(h + kk);
    bf16x8 wv = *(const bf16x8*)(w + kk);
#pragma unroll
    for (int j = 0; j < 8; ++j)
      acc += bf2f(((u16*)&hv)[j]) * bf2f(((u16*)&wv)[j]);
  }
  acc += __shfl_xor(acc, 1);
  acc += __shfl_xor(acc, 2);
  if (ks == 0) p.out[((size_t)b * SEQ + tq) * OUTD + o] = acc + p.fcb[o];
}

__global__ __launch_bounds__(NTHR, 2)
void k_lstm(Params p) {
  extern __shared__ char smem[];
  const int blk = blockIdx.x, tid = threadIdx.x;
  const int lane = tid & 63, wave = tid >> 6;

  u16* lw0 = (u16*)smem;
  u16* lw1 = (u16*)(smem + 65536);
  float* slab = (float*)(smem + 131072) + wave * 320;

  // one-time: block's W slices -> LDS (linear, frag-ordered)
  {
    const u16* g0 = p.w0f + (size_t)blk * 32768;
    const u16* g1 = p.w1f + (size_t)blk * 32768;
    for (int i = tid * 8; i < 32768; i += NTHR * 8) {
      *(bf16x8*)(lw0 + i) = *(const bf16x8*)(g0 + i);
      *(bf16x8*)(lw1 + i) = *(const bf16x8*)(g1 + i);
    }
  }
  // per-lane bias preload; register-resident cell state
  const int jg = blk * 4 + ((lane >> 2) & 3);
  float b0r[4], bxr[4], b1r[4];
  float c0r[4] = {0,0,0,0}, c1r[4] = {0,0,0,0};
#pragma unroll
  for (int g = 0; g < 4; ++g) {
    b0r[g] = p.bias0b[4 * jg + g];
    bxr[g] = p.bias0x[4 * jg + g];
    b1r[g] = p.bias1[4 * jg + g];
  }
  __syncthreads();

  u16* h0buf[2] = { p.h0a, p.h0b };
  u16* h1buf[2] = { p.h1a, p.h1b };
  int bar = 0;

  for (int t = 0; t < SEQ; ++t) {
    const int pr = t & 1;
    // ---- phase A: gates0 = [h0(t-1) | h1(t-1)] @ W0^T ; cell0 -> h0(t) ----
    if (t > 0) out_proj(h1buf[pr], p, blk, lane, wave, t - 1);
    gemm_cell(h0buf[pr], h1buf[pr], lw0, c0r, h0buf[pr ^ 1],
              b0r, bxr, t > 0, blk, lane, wave, slab);
    gbar(p.flags, bar++, blk, tid);
    // ---- phase B: gates1 = [h0(t) | h1(t-1)] @ W1^T ; cell1 -> h1(t) ----
    gemm_cell(h0buf[pr ^ 1], (t == 0) ? p.h1i : h1buf[pr], lw1, c1r, h1buf[pr ^ 1],
              b1r, nullptr, false, blk, lane, wave, slab);
    gbar(p.flags, bar++, blk, tid);
  }
  out_proj(h1buf[0], p, blk, lane, wave, SEQ - 1);   // h1(255) lives in buffer 0
}

// ---------------- launch ----------------

extern "C" void kernel_launch(void* const* d_in, const int* in_sizes, int n_in,
                              void* d_out, int out_size, void* d_ws, size_t ws_size,
                              hipStream_t stream) {
  const float* zs   = (const float*)d_in[0];
  const float* zk   = (const float*)d_in[1];
  const float* fiw  = (const float*)d_in[2];
  const float* fib  = (const float*)d_in[3];
  const float* Wih0 = (const float*)d_in[4];
  const float* Whh0 = (const float*)d_in[5];
  const float* bih0 = (const float*)d_in[6];
  const float* bhh0 = (const float*)d_in[7];
  const float* Wih1 = (const float*)d_in[8];
  const float* Whh1 = (const float*)d_in[9];
  const float* bih1 = (const float*)d_in[10];
  const float* bhh1 = (const float*)d_in[11];
  const float* fcw  = (const float*)d_in[12];
  const float* fcb  = (const float*)d_in[13];
  float* out = (float*)d_out;

  char* ws = (char*)d_ws;
  size_t off = 0;
  auto alloc = [&](size_t bytes) -> char* {
    char* pp = ws + off;
    off += (bytes + 255) & ~(size_t)255;
    return pp;
  };
  u16* w0f  = (u16*)alloc((size_t)NGATE * 2048 * 2);
  u16* w1f  = (u16*)alloc((size_t)NGATE * 2048 * 2);
  u16* h0a  = (u16*)alloc((size_t)BATCH * HID * 2);
  u16* h0b  = (u16*)alloc((size_t)BATCH * HID * 2);
  u16* h1a  = (u16*)alloc((size_t)BATCH * HID * 2);
  u16* h1b  = (u16*)alloc((size_t)BATCH * HID * 2);
  u16* h1i  = (u16*)alloc((size_t)BATCH * HID * 2);
  u16* fcwb = (u16*)alloc((size_t)OUTD * HID * 2);
  float* bias0b = (float*)alloc(NGATE * 4);
  float* bias0x = (float*)alloc(NGATE * 4);
  float* bias1  = (float*)alloc(NGATE * 4);
  unsigned* flags = (unsigned*)alloc((size_t)2 * SEQ * NBLK * 4);

  hipMemsetAsync(flags, 0, (size_t)2 * SEQ * NBLK * 4, stream);

  hipLaunchKernelGGL(k_build_w0f, dim3(NGATE), dim3(256), 0, stream, Whh0, Wih0, fcw, w0f);
  hipLaunchKernelGGL(k_build_w1f, dim3(NGATE), dim3(256), 0, stream, Wih1, Whh1, w1f);
  hipLaunchKernelGGL(k_build_bias, dim3(16), dim3(256), 0, stream,
                     bih0, bhh0, bih1, bhh1, Wih0, fcb, bias0b, bias0x, bias1);
  hipLaunchKernelGGL(k_fcwb, dim3(256), dim3(256), 0, stream, fcw, fcwb);
  hipLaunchKernelGGL(k_init, dim3(BATCH), dim3(256), 0, stream, zs, zk, fiw, fib, h0a, h1a, h1i);

  Params prm;
  prm.w0f = w0f; prm.w1f = w1f;
  prm.bias0b = bias0b; prm.bias0x = bias0x; prm.bias1 = bias1;
  prm.h0a = h0a; prm.h0b = h0b; prm.h1a = h1a; prm.h1b = h1b; prm.h1i = h1i;
  prm.fcwb = fcwb; prm.fcb = fcb; prm.out = out;
  prm.flags = flags;

  hipFuncSetAttribute((const void*)k_lstm, hipFuncAttributeMaxDynamicSharedMemorySize, LDS_BYTES);
  void* args[] = { &prm };
  hipLaunchCooperativeKernel((void*)k_lstm, dim3(NBLK), dim3(NTHR), args, LDS_BYTES, stream);
}